// Round 7
// baseline (219.648 us; speedup 1.0000x reference)
//
#include <hip/hip_runtime.h>
#include <hip/hip_bf16.h>
#include <stdint.h>

// B=8, N=1024, D=1024.  out = relu(adj @ (y@W) / adj_sumrow + b + x)
// R10: prep elimination. The K-loop is invariant (~40us) across every
// schedule tried (R3-R9: occupancy, waves, prefetch depth, barriers, issue
// uniformity) — so attack the orthogonal ~28us prep pass instead: fuse the
// f32->bf16 conversion INTO the GEMM staging (reg-staged operand: f32 load ->
// f2bf -> swizzled ds_write_b128), leaving only a tiny W-transpose prep.
// gemm1: A=Wt gload_lds, B=y f32 reg-staged.  gemm2: A=adj f32 reg-staged,
// B=sup2 gload_lds.  One barrier per K-tile; waits land on ops issued a full
// tile earlier. Same f2bf rounding as before -> identical numerics.

typedef float  f32x4  __attribute__((ext_vector_type(4)));
typedef __bf16 bf16x8 __attribute__((ext_vector_type(8)));

__device__ __forceinline__ unsigned int f2bf(float f) {
  union { float f; unsigned int u; } c; c.f = f;
  unsigned int u = c.u;
  u += 0x7FFFu + ((u >> 16) & 1u);   // RNE; inputs finite
  return u >> 16;
}

__device__ __forceinline__ void async_cp16(const void* g, void* l) {
  __builtin_amdgcn_global_load_lds(
      (const __attribute__((address_space(1))) unsigned int*)g,
      (__attribute__((address_space(3))) unsigned int*)l, 16, 0, 0);
}

__device__ __forceinline__ void bar() { asm volatile("s_barrier" ::: "memory"); }
#define VMCNT0()  asm volatile("s_waitcnt vmcnt(0)" ::: "memory")
#define LGKM0()   asm volatile("s_waitcnt lgkmcnt(0)" ::: "memory")

// ---------------- W transpose+cvt only (tiny) ----------------

__global__ __launch_bounds__(256) void k_prep_w(
    const float* __restrict__ W, unsigned short* __restrict__ Wt)
{
  __shared__ float t[64][65];
  const int id = blockIdx.x;
  const int n0 = (id & 15) * 64, k0 = (id >> 4) * 64;
  const int tx = threadIdx.x & 63, ty = threadIdx.x >> 6;
#pragma unroll
  for (int r = ty; r < 64; r += 4)
    t[r][tx] = W[(size_t)(k0 + r) * 1024 + n0 + tx];
  __syncthreads();
#pragma unroll
  for (int r = ty; r < 64; r += 4)
    Wt[(size_t)(n0 + r) * 1024 + k0 + tx] = (unsigned short)f2bf(t[tx][r]);
}

// ---------------- shared GEMM pieces: 256x128 tile, BK=64 ----------------
// LDS buf (48KB x2): A[256][64] bf16 at +0, B[128][64] at +16384 (ushort idx).
// Row = 128B = 8 chunks of 16B; physical chunk = (logical + row) & 7.
// gload_lds side: linear dest + inverse-swizzled source column (proven R3+).
// reg-staged side: swizzle applied directly on the ds_write address.

// fragment read + 32 MFMA, h-split to cap register pressure
__device__ __forceinline__ void compute_tile(
    const unsigned short* la, const unsigned short* lb,
    f32x4 acc[4][4], int wm, int wn, int quad, int l16)
{
#pragma unroll
  for (int h = 0; h < 2; ++h) {
    bf16x8 af[4], bfr[4];
#pragma unroll
    for (int i = 0; i < 4; ++i) {
      const int r = wm + i * 16 + l16;
      af[i] = *(const bf16x8*)(la + r * 64 + ((h * 4 + quad + r) & 7) * 8);
    }
#pragma unroll
    for (int j = 0; j < 4; ++j) {
      const int r = wn + j * 16 + l16;
      bfr[j] = *(const bf16x8*)(lb + r * 64 + ((h * 4 + quad + r) & 7) * 8);
    }
    __builtin_amdgcn_s_setprio(1);
#pragma unroll
    for (int i = 0; i < 4; ++i)
#pragma unroll
      for (int j = 0; j < 4; ++j)
        acc[i][j] = __builtin_amdgcn_mfma_f32_16x16x32_bf16(
            af[i], bfr[j], acc[i][j], 0, 0, 0);
    __builtin_amdgcn_s_setprio(0);
  }
}

__device__ __forceinline__ void zero_acc(f32x4 acc[4][4]) {
#pragma unroll
  for (int i = 0; i < 4; ++i)
#pragma unroll
    for (int j = 0; j < 4; ++j)
#pragma unroll
      for (int r = 0; r < 4; ++r) acc[i][j][r] = 0.0f;
}

// ---------------- GEMM1: Sup2[d][b*1024+n] = (y@W)^T ----------------
// A = Wt [1024][1024] bf16 (gload_lds, 256 rows: 4 inst/wave/tile)
// B = y  [8192][1024] f32  (reg-staged, 128 rows: 4 dwordx4 + 16 cvt +
//                           2 ds_write_b128 per thread per tile)
// 256 blocks; xcd owns a contiguous 1024-row y slice (+Wt) for L2 locality.

__global__ __launch_bounds__(512, 2) void k_gemm1(
    const unsigned short* __restrict__ Wt,
    const float* __restrict__ Y,
    unsigned short* __restrict__ Sup2)
{
  __shared__ __align__(16) unsigned short lsm[2 * 24576];  // 96 KB
  const int tid = threadIdx.x;
  const int xcd = blockIdx.x & 7, slot = blockIdx.x >> 3;  // slot 0..31
  const int m0 = (slot >> 3) * 256;
  const int n0 = (xcd * 8 + (slot & 7)) * 128;             // y row base

  const int lane = tid & 63, wave = tid >> 6;
  const int wm = (wave >> 1) * 64, wn = (wave & 1) * 64;
  const int quad = lane >> 4, l16 = lane & 15;
  const int rg = lane >> 3;
  const int colo = (((lane & 7) - rg) & 7) * 8;   // inverse swizzle for gload_lds

  // reg-stage constants (B): thread owns chunks q = tid + s*512, s=0..1
  const int r0 = tid >> 3;              // 0..63 (row base; +64 for s=1)
  const int cb = tid & 7;               // logical chunk
  const int pb = (cb + r0) & 7;         // physical chunk ((row&7)==(r0&7))

  f32x4 acc[4][4];
  zero_acc(acc);

  float4 br[2][2];   // staged B f32 [s][half]

  auto stageA = [&](int k0, unsigned short* la) {
#pragma unroll
    for (int s = 0; s < 4; ++s) {
      const int row0 = (wave * 4 + s) * 8;
      async_cp16(Wt + (size_t)(m0 + row0 + rg) * 1024 + k0 + colo, la + row0 * 64);
    }
  };
  auto loadB = [&](int k0) {
#pragma unroll
    for (int s = 0; s < 2; ++s) {
      const float* p = Y + (size_t)(n0 + r0 + 64 * s) * 1024 + k0 + cb * 8;
      br[s][0] = *(const float4*)p;
      br[s][1] = *(const float4*)(p + 4);
    }
  };
  auto writeB = [&](unsigned short* lb) {
#pragma unroll
    for (int s = 0; s < 2; ++s) {
      uint4 pk;
      pk.x = f2bf(br[s][0].x) | (f2bf(br[s][0].y) << 16);
      pk.y = f2bf(br[s][0].z) | (f2bf(br[s][0].w) << 16);
      pk.z = f2bf(br[s][1].x) | (f2bf(br[s][1].y) << 16);
      pk.w = f2bf(br[s][1].z) | (f2bf(br[s][1].w) << 16);
      *(uint4*)(lb + (r0 + 64 * s) * 64 + pb * 8) = pk;
    }
  };

  unsigned short* buf0 = lsm;
  unsigned short* buf1 = lsm + 24576;

  // prologue: tile 0
  stageA(0, buf0);
  loadB(0);
  writeB(buf0 + 16384);
  VMCNT0(); LGKM0();
  __builtin_amdgcn_sched_barrier(0);
  bar();

#pragma unroll 1
  for (int T = 0; T < 16; ++T) {
    unsigned short* cb_ = (T & 1) ? buf1 : buf0;
    unsigned short* nb_ = (T & 1) ? buf0 : buf1;
    if (T < 15) { stageA((T + 1) * 64, nb_); loadB((T + 1) * 64); }
    compute_tile(cb_, cb_ + 16384, acc, wm, wn, quad, l16);
    if (T < 15) {
      writeB(nb_ + 16384);
      VMCNT0(); LGKM0();
      __builtin_amdgcn_sched_barrier(0);
      bar();
    }
  }

#pragma unroll
  for (int mi = 0; mi < 4; ++mi) {
    const int mb = m0 + wm + mi * 16 + quad * 4;
#pragma unroll
    for (int r = 0; r < 4; ++r) {
      unsigned short* row = Sup2 + ((size_t)(mb + r) << 13);
#pragma unroll
      for (int nj = 0; nj < 4; ++nj)
        row[n0 + wn + nj * 16 + l16] = (unsigned short)f2bf(acc[mi][nj][r]);
    }
  }
}

// ------- GEMM2: out = relu(adj@support / rowsum + bias + x) -------
// A = adj[b] [1024][1024] f32 (reg-staged, 256 rows: 8 dwordx4 + 32 cvt +
//                              4 ds_write_b128 per thread per tile)
// B = Sup2 b-slice, row stride 8192, bf16 (gload_lds, 128 rows: 2 inst/wave)
// 256 blocks; xcd owns batch b.

__global__ __launch_bounds__(512, 2) void k_gemm2(
    const float* __restrict__ Adj,            // [8][1024][1024] f32
    const unsigned short* __restrict__ Sup2,  // [1024][8192] bf16
    const float* __restrict__ x,
    const float* __restrict__ sumrow,         // [8][1024]
    const float* __restrict__ bias,           // [1024]
    float* __restrict__ out)
{
  __shared__ __align__(16) unsigned short lsm[2 * 24576];  // 96 KB
  const int tid = threadIdx.x;
  const int b = blockIdx.x & 7, slot = blockIdx.x >> 3;    // slot 0..31
  const int m0 = (slot >> 3) * 256, n0 = (slot & 7) * 128;

  const float* Ab = Adj + ((size_t)b << 20);
  const unsigned short* Bt = Sup2 + ((size_t)b << 10);     // row stride 8192

  const int lane = tid & 63, wave = tid >> 6;
  const int wm = (wave >> 1) * 64, wn = (wave & 1) * 64;
  const int quad = lane >> 4, l16 = lane & 15;
  const int rg = lane >> 3;
  const int colo = (((lane & 7) - rg) & 7) * 8;

  const int r0 = tid >> 3;              // 0..63 (row base; +64s, s=0..3)
  const int ca = tid & 7;
  const int pa = (ca + r0) & 7;

  f32x4 acc[4][4];
  zero_acc(acc);

  float4 ar[4][2];   // staged A f32 [s][half]

  auto loadA = [&](int k0) {
#pragma unroll
    for (int s = 0; s < 4; ++s) {
      const float* p = Ab + (size_t)(m0 + r0 + 64 * s) * 1024 + k0 + ca * 8;
      ar[s][0] = *(const float4*)p;
      ar[s][1] = *(const float4*)(p + 4);
    }
  };
  auto writeA = [&](unsigned short* la) {
#pragma unroll
    for (int s = 0; s < 4; ++s) {
      uint4 pk;
      pk.x = f2bf(ar[s][0].x) | (f2bf(ar[s][0].y) << 16);
      pk.y = f2bf(ar[s][0].z) | (f2bf(ar[s][0].w) << 16);
      pk.z = f2bf(ar[s][1].x) | (f2bf(ar[s][1].y) << 16);
      pk.w = f2bf(ar[s][1].z) | (f2bf(ar[s][1].w) << 16);
      *(uint4*)(la + (r0 + 64 * s) * 64 + pa * 8) = pk;
    }
  };
  auto stageB = [&](int k0, unsigned short* lb) {
#pragma unroll
    for (int s = 0; s < 2; ++s) {
      const int row0 = (wave * 2 + s) * 8;
      async_cp16(Bt + (size_t)(n0 + row0 + rg) * 8192 + k0 + colo, lb + row0 * 64);
    }
  };

  unsigned short* buf0 = lsm;
  unsigned short* buf1 = lsm + 24576;

  // prologue: tile 0
  loadA(0);
  stageB(0, buf0 + 16384);
  writeA(buf0);
  VMCNT0(); LGKM0();
  __builtin_amdgcn_sched_barrier(0);
  bar();

#pragma unroll 1
  for (int T = 0; T < 16; ++T) {
    unsigned short* cb_ = (T & 1) ? buf1 : buf0;
    unsigned short* nb_ = (T & 1) ? buf0 : buf1;
    if (T < 15) { loadA((T + 1) * 64); stageB((T + 1) * 64, nb_ + 16384); }
    compute_tile(cb_, cb_ + 16384, acc, wm, wn, quad, l16);
    if (T < 15) {
      writeA(nb_);
      VMCNT0(); LGKM0();
      __builtin_amdgcn_sched_barrier(0);
      bar();
    }
  }

  const float* xb = x   + ((size_t)b << 20);
  float*       ob = out + ((size_t)b << 20);
  const float* sr = sumrow + ((size_t)b << 10);

  float bv[4];
#pragma unroll
  for (int nj = 0; nj < 4; ++nj) bv[nj] = bias[n0 + wn + nj * 16 + l16];

#pragma unroll
  for (int mi = 0; mi < 4; ++mi) {
    const int mb = m0 + wm + mi * 16 + quad * 4;
#pragma unroll
    for (int r = 0; r < 4; ++r) {
      const int m = mb + r;
      const float inv = 1.0f / sr[m];
#pragma unroll
      for (int nj = 0; nj < 4; ++nj) {
        const int n = n0 + wn + nj * 16 + l16;
        const size_t idx = (((size_t)m) << 10) + n;
        float v = acc[mi][nj][r] * inv + bv[nj] + xb[idx];
        ob[idx] = fmaxf(v, 0.0f);
      }
    }
  }
}

// ---------------- launcher ----------------

extern "C" void kernel_launch(void* const* d_in, const int* in_sizes, int n_in,
                              void* d_out, int out_size, void* d_ws, size_t ws_size,
                              hipStream_t stream) {
  const float* x      = (const float*)d_in[0];
  const float* y      = (const float*)d_in[1];
  const float* adj    = (const float*)d_in[2];
  const float* sumrow = (const float*)d_in[3];
  const float* W      = (const float*)d_in[4];
  const float* bias   = (const float*)d_in[5];
  float* out = (float*)d_out;

  char* ws = (char*)d_ws;
  unsigned short* wt   = (unsigned short*)(ws);                      //  2 MB
  unsigned short* sup2 = (unsigned short*)(ws + ((size_t)2 << 20));  // 16 MB

  k_prep_w<<<dim3(256), dim3(256), 0, stream>>>(W, wt);
  k_gemm1<<<dim3(256), dim3(512), 0, stream>>>(wt, y, sup2);
  k_gemm2<<<dim3(256), dim3(512), 0, stream>>>(adj, sup2, x, sumrow, bias, out);
}

// Round 8
// 197.631 us; speedup vs baseline: 1.1114x; 1.1114x over previous
//
#include <hip/hip_runtime.h>
#include <hip/hip_bf16.h>
#include <stdint.h>

// B=8, N=1024, D=1024.  out = relu(adj @ (y@W) / adj_sumrow + b + x)
// R11: R8 gemms verbatim (best measured: K-loop invariant at ~40us across
// R3-R10 structural sweep). Prep rewritten for BW: 2048 grid-strided blocks
// (8 float4/thread, 8 blk/CU) instead of 16640 one-shot blocks (was 3.6 TB/s,
// no ILP); W-transpose folded in as blocks [2048,2304).

typedef float  f32x4  __attribute__((ext_vector_type(4)));
typedef __bf16 bf16x8 __attribute__((ext_vector_type(8)));

__device__ __forceinline__ unsigned short f2bf(float f) {
  union { float f; unsigned int u; } c; c.f = f;
  unsigned int u = c.u;
  u += 0x7FFFu + ((u >> 16) & 1u);   // RNE; inputs finite
  return (unsigned short)(u >> 16);
}

__device__ __forceinline__ void async_cp16(const void* g, void* l) {
  __builtin_amdgcn_global_load_lds(
      (const __attribute__((address_space(1))) unsigned int*)g,
      (__attribute__((address_space(3))) unsigned int*)l, 16, 0, 0);
}

__device__ __forceinline__ void bar() { asm volatile("s_barrier" ::: "memory"); }
#define VMCNT(n) asm volatile("s_waitcnt vmcnt(" #n ")" ::: "memory")

// ---------------- prep: grid-strided cvt + W transpose ----------------
// blocks [0,1024): y f32->bf16, 8 float4/thread grid-strided
// blocks [1024,2048): adj f32->bf16
// blocks [2048,2304): W transpose+cvt (64x64 tiles)

__global__ __launch_bounds__(256) void k_prep(
    const float4* __restrict__ y4, const float4* __restrict__ a4,
    ushort4* __restrict__ yb, ushort4* __restrict__ ab,
    const float* __restrict__ W, unsigned short* __restrict__ Wt)
{
  const int bid = blockIdx.x;
  if (bid < 2048) {
    const bool isY = bid < 1024;
    const float4* __restrict__ src = isY ? y4 : a4;
    ushort4* __restrict__ dst = isY ? yb : ab;
    int idx = (bid & 1023) * 256 + (int)threadIdx.x;
#pragma unroll
    for (int it = 0; it < 8; ++it, idx += 262144) {
      const float4 v = src[idx];
      ushort4 p;
      p.x = f2bf(v.x); p.y = f2bf(v.y); p.z = f2bf(v.z); p.w = f2bf(v.w);
      dst[idx] = p;
    }
  } else {
    __shared__ float t[64][65];
    const int id = bid - 2048;
    const int n0 = (id & 15) * 64, k0 = (id >> 4) * 64;
    const int tx = threadIdx.x & 63, ty = threadIdx.x >> 6;
#pragma unroll
    for (int r = ty; r < 64; r += 4)
      t[r][tx] = W[(size_t)(k0 + r) * 1024 + n0 + tx];
    __syncthreads();
#pragma unroll
    for (int r = ty; r < 64; r += 4)
      Wt[(size_t)(n0 + r) * 1024 + k0 + tx] = f2bf(t[tx][r]);
  }
}

// ---------------- GEMM pieces: 256x128 tile, BK=64, 8 waves (R8) ----------
// LDS row = 128B = 8 chunks of 16B; physical chunk = (logical + row) & 7.
// Staging applies the inverse permutation on the global k-column; all staging
// row bases are multiples of 8 so the mod-8 algebra is unchanged (proven R3+).
//
// A-tile 256x64 = 32KB, two 16KB chunks: chunk c = rows with (r>>5)&1 == c
// (matches quadrant mh row sets under the 4Mx2N wave split).
// B-tile 128x64 = 16KB, one chunk (all rows).

__device__ __forceinline__ void stageA(
    const unsigned short* __restrict__ A, int sA, int m0, int k0, int c,
    unsigned short* la, int wave, int rg, int colo)
{
#pragma unroll
  for (int s = 0; s < 2; ++s) {
    const int t = wave * 2 + s;                        // 0..15
    const int row0 = (t >> 2) * 64 + c * 32 + (t & 3) * 8;
    async_cp16(A + (size_t)(m0 + row0 + rg) * sA + k0 + colo, la + row0 * 64);
  }
}

__device__ __forceinline__ void stageB(
    const unsigned short* __restrict__ Bt, int sB, int n0, int k0,
    unsigned short* lb, int wave, int rg, int colo)
{
#pragma unroll
  for (int s = 0; s < 2; ++s) {
    const int t = wave * 2 + s;                        // 0..15
    const int row0 = t * 8;
    async_cp16(Bt + (size_t)(n0 + row0 + rg) * sB + k0 + colo, lb + row0 * 64);
  }
}

__device__ __forceinline__ void readA(
    const unsigned short* la, bf16x8 af[2][2], int wm, int mh, int quad, int l16)
{
#pragma unroll
  for (int h = 0; h < 2; ++h)
#pragma unroll
    for (int i = 0; i < 2; ++i) {
      const int r = wm + mh * 32 + i * 16 + l16;
      af[h][i] = *(const bf16x8*)(la + r * 64 + ((h * 4 + quad + r) & 7) * 8);
    }
}

__device__ __forceinline__ void readB(
    const unsigned short* lb, bf16x8 bfr[2][2], int wn, int nh, int quad, int l16)
{
#pragma unroll
  for (int h = 0; h < 2; ++h)
#pragma unroll
    for (int j = 0; j < 2; ++j) {
      const int r = wn + nh * 32 + j * 16 + l16;
      bfr[h][j] = *(const bf16x8*)(lb + r * 64 + ((h * 4 + quad + r) & 7) * 8);
    }
}

__device__ __forceinline__ void quad8(
    bf16x8 af[2][2], bf16x8 bfr[2][2], f32x4 acc[4][4], int mh, int nh)
{
  __builtin_amdgcn_s_setprio(1);
#pragma unroll
  for (int h = 0; h < 2; ++h)
#pragma unroll
    for (int i = 0; i < 2; ++i)
#pragma unroll
      for (int j = 0; j < 2; ++j)
        acc[mh * 2 + i][nh * 2 + j] = __builtin_amdgcn_mfma_f32_16x16x32_bf16(
            af[h][i], bfr[h][j], acc[mh * 2 + i][nh * 2 + j], 0, 0, 0);
  __builtin_amdgcn_s_setprio(0);
}

// 16 K-tiles, double-buffered. Per tile T (steady state):
//  ph0: issue A0(T+1); vmcnt(4); bar; q00
//  ph1: issue B(T+1);  no wait;       q01 (af carried)
//  ph2: issue A1(T+1); vmcnt(6); bar; q11 (bfr carried)
//  ph3: no wait, no barrier;          q10
__device__ __forceinline__ void gemm256x128(
    const unsigned short* __restrict__ A,  int sA,
    const unsigned short* __restrict__ Bt, int sB,
    int m0, int n0, f32x4 acc[4][4], unsigned short* lsm, int tid)
{
  const int lane = tid & 63, wave = tid >> 6;
  const int wm = (wave >> 1) * 64, wn = (wave & 1) * 64;
  const int quad = lane >> 4, l16 = lane & 15;
  const int rg = lane >> 3;
  const int colo = (((lane & 7) - rg) & 7) * 8;   // inverse-swizzled k-offset

  bf16x8 af[2][2], bfr[2][2];

  // prologue: tile 0, issue order A0,B,A1 (matches steady-state drain order)
  stageA(A, sA, m0, 0, 0, lsm, wave, rg, colo);
  stageB(Bt, sB, n0, 0, lsm + 16384, wave, rg, colo);
  stageA(A, sA, m0, 0, 1, lsm, wave, rg, colo);

#pragma unroll 1
  for (int T = 0; T < 15; ++T) {
    const unsigned short* la = lsm + (T & 1) * 24576;
    const unsigned short* lb = la + 16384;
    unsigned short* na = lsm + ((T + 1) & 1) * 24576;
    unsigned short* nb = na + 16384;
    const int nk = (T + 1) * 64;

    // ph0 (q00)
    stageA(A, sA, m0, nk, 0, na, wave, rg, colo);
    VMCNT(4); bar();
    readA(la, af, wm, 0, quad, l16);
    readB(lb, bfr, wn, 0, quad, l16);
    quad8(af, bfr, acc, 0, 0);

    // ph1 (q01): B fully resident; af register-carried
    stageB(Bt, sB, n0, nk, nb, wave, rg, colo);
    readB(lb, bfr, wn, 1, quad, l16);
    quad8(af, bfr, acc, 0, 1);

    // ph2 (q11): needs A1(T); bfr register-carried
    stageA(A, sA, m0, nk, 1, na, wave, rg, colo);
    VMCNT(6); bar();
    readA(la, af, wm, 1, quad, l16);
    quad8(af, bfr, acc, 1, 1);

    // ph3 (q10): everything resident -> no wait, no barrier
    readB(lb, bfr, wn, 0, quad, l16);
    quad8(af, bfr, acc, 1, 0);
  }

  // tail: tile 15, nothing left to stage; tightening counts
  {
    const unsigned short* la = lsm + 24576;   // 15&1 == 1
    const unsigned short* lb = la + 16384;
    VMCNT(2); bar();
    readA(la, af, wm, 0, quad, l16);
    readB(lb, bfr, wn, 0, quad, l16);
    quad8(af, bfr, acc, 0, 0);
    readB(lb, bfr, wn, 1, quad, l16);
    quad8(af, bfr, acc, 0, 1);
    VMCNT(0); bar();
    readA(la, af, wm, 1, quad, l16);
    quad8(af, bfr, acc, 1, 1);
    readB(lb, bfr, wn, 0, quad, l16);
    quad8(af, bfr, acc, 1, 0);
  }
}

__device__ __forceinline__ void zero_acc(f32x4 acc[4][4]) {
#pragma unroll
  for (int i = 0; i < 4; ++i)
#pragma unroll
    for (int j = 0; j < 4; ++j)
#pragma unroll
      for (int r = 0; r < 4; ++r) acc[i][j][r] = 0.0f;
}

// ---------------- GEMM1: Sup2[d][b*1024+n] = (y@W)^T ----------------
// 256 blocks; xcd = bid&7 owns 8 consecutive n-tiles -> per-XCD working set
// Wt (2MB) + ybf n-slice (2MB) = one L2.

__global__ __launch_bounds__(512, 2) void k_gemm1(
    const unsigned short* __restrict__ Wt,    // [1024][1024]
    const unsigned short* __restrict__ Ybf,   // [8192][1024]
    unsigned short* __restrict__ Sup2)        // [1024][8192]
{
  __shared__ __align__(16) unsigned short lsm[49152];  // 96 KB
  const int tid = threadIdx.x;
  const int xcd = blockIdx.x & 7, slot = blockIdx.x >> 3;  // slot 0..31
  const int m0 = (slot >> 3) * 256;                        // 4 m-tiles
  const int n0 = (xcd * 8 + (slot & 7)) * 128;             // 64 n-tiles

  f32x4 acc[4][4];
  zero_acc(acc);
  gemm256x128(Wt, 1024, Ybf, 1024, m0, n0, acc, lsm, tid);

  const int lane = tid & 63, wave = tid >> 6;
  const int wm = (wave >> 1) * 64, wn = (wave & 1) * 64;
  const int quad = lane >> 4, l16 = lane & 15;
#pragma unroll
  for (int mi = 0; mi < 4; ++mi) {
    const int mb = m0 + wm + mi * 16 + quad * 4;
#pragma unroll
    for (int r = 0; r < 4; ++r) {
      unsigned short* row = Sup2 + ((size_t)(mb + r) << 13);
#pragma unroll
      for (int nj = 0; nj < 4; ++nj)
        row[n0 + wn + nj * 16 + l16] = f2bf(acc[mi][nj][r]);
    }
  }
}

// ------- GEMM2: out = relu(adj@support / rowsum + bias + x) -------
// 256 blocks; xcd = bid&7 owns batch b -> adjbf[b] (2MB) + sup2 b-slice (2MB)
// = one L2.

__global__ __launch_bounds__(512, 2) void k_gemm2(
    const unsigned short* __restrict__ AdjBf, // [8][1024][1024]
    const unsigned short* __restrict__ Sup2,  // [1024][8192]
    const float* __restrict__ x,
    const float* __restrict__ sumrow,         // [8][1024]
    const float* __restrict__ bias,           // [1024]
    float* __restrict__ out)
{
  __shared__ __align__(16) unsigned short lsm[49152];  // 96 KB
  const int tid = threadIdx.x;
  const int b = blockIdx.x & 7, slot = blockIdx.x >> 3;  // slot 0..31
  const int m0 = (slot >> 3) * 256, n0 = (slot & 7) * 128;

  f32x4 acc[4][4];
  zero_acc(acc);
  gemm256x128(AdjBf + ((size_t)b << 20), 1024,
              Sup2 + ((size_t)b << 10), 8192,
              m0, n0, acc, lsm, tid);

  const float* xb = x   + ((size_t)b << 20);
  float*       ob = out + ((size_t)b << 20);
  const float* sr = sumrow + ((size_t)b << 10);
  const int lane = tid & 63, wave = tid >> 6;
  const int wm = (wave >> 1) * 64, wn = (wave & 1) * 64;
  const int quad = lane >> 4, l16 = lane & 15;

  float bv[4];
#pragma unroll
  for (int nj = 0; nj < 4; ++nj) bv[nj] = bias[n0 + wn + nj * 16 + l16];

#pragma unroll
  for (int mi = 0; mi < 4; ++mi) {
    const int mb = m0 + wm + mi * 16 + quad * 4;
#pragma unroll
    for (int r = 0; r < 4; ++r) {
      const int m = mb + r;
      const float inv = 1.0f / sr[m];
#pragma unroll
      for (int nj = 0; nj < 4; ++nj) {
        const int n = n0 + wn + nj * 16 + l16;
        const size_t idx = (((size_t)m) << 10) + n;
        float v = acc[mi][nj][r] * inv + bv[nj] + xb[idx];
        ob[idx] = fmaxf(v, 0.0f);
      }
    }
  }
}

// ---------------- launcher ----------------

extern "C" void kernel_launch(void* const* d_in, const int* in_sizes, int n_in,
                              void* d_out, int out_size, void* d_ws, size_t ws_size,
                              hipStream_t stream) {
  const float* x      = (const float*)d_in[0];
  const float* y      = (const float*)d_in[1];
  const float* adj    = (const float*)d_in[2];
  const float* sumrow = (const float*)d_in[3];
  const float* W      = (const float*)d_in[4];
  const float* bias   = (const float*)d_in[5];
  float* out = (float*)d_out;

  char* ws = (char*)d_ws;
  unsigned short* ybf   = (unsigned short*)(ws);                       // 16 MB
  unsigned short* adjbf = (unsigned short*)(ws + ((size_t)16 << 20));  // 16 MB
  unsigned short* wt    = (unsigned short*)(ws + ((size_t)32 << 20));  //  2 MB
  unsigned short* sup2  = (unsigned short*)(ws + ((size_t)34 << 20));  // 16 MB

  k_prep<<<dim3(2304), dim3(256), 0, stream>>>(
      (const float4*)y, (const float4*)adj, (ushort4*)ybf, (ushort4*)adjbf, W, wt);
  k_gemm1<<<dim3(256), dim3(512), 0, stream>>>(wt, ybf, sup2);
  k_gemm2<<<dim3(256), dim3(512), 0, stream>>>(adjbf, sup2, x, sumrow, bias, out);
}